// Round 10
// baseline (720.158 us; speedup 1.0000x reference)
//
#include <hip/hip_runtime.h>
#include <hip/hip_bf16.h>
#include <math.h>

#define S_LEN 2048
#define BATCH 2
#define HID 1024
#define NHEAD 16
#define HDIM 64
#define NTOK (S_LEN*BATCH)   // 4096

typedef __bf16 bf16;
typedef __bf16 bf16x4 __attribute__((ext_vector_type(4)));
typedef __bf16 bf16x8 __attribute__((ext_vector_type(8)));
typedef float f32x4 __attribute__((ext_vector_type(4)));

typedef const __attribute__((address_space(1))) unsigned int* gptr_t;
typedef __attribute__((address_space(3))) unsigned int* lptr_t;

__device__ __forceinline__ void gload16(const void* g, void* l) {
    __builtin_amdgcn_global_load_lds((gptr_t)g, (lptr_t)l, 16, 0, 0);
}

// ---------------- fp32 -> bf16 convert (8 elems/thread) ----------------
__global__ void cvt_f32_bf16(const float* __restrict__ src, bf16* __restrict__ dst, int n) {
    int i = (blockIdx.x * blockDim.x + threadIdx.x) * 8;
    if (i >= n) return;
    const float4* s = (const float4*)(src + i);
    float4 a = s[0], b = s[1];
    bf16x8 o;
    o[0] = (bf16)a.x; o[1] = (bf16)a.y; o[2] = (bf16)a.z; o[3] = (bf16)a.w;
    o[4] = (bf16)b.x; o[5] = (bf16)b.y; o[6] = (bf16)b.z; o[7] = (bf16)b.w;
    *(bf16x8*)(dst + i) = o;
}

// ---------------- GEMM: C[M][N] = A[M][K] * B[N][K]^T ----------------
#define BM 128
#define BN 128
#define BK 32

__global__ __launch_bounds__(256) void gemm_bt(
    const bf16* __restrict__ A, const bf16* __restrict__ B,
    int M, int N, int K, int mode,
    const float* __restrict__ bq, const float* __restrict__ bk,
    const float* __restrict__ bv, const float* __restrict__ bo,
    bf16* __restrict__ qh, bf16* __restrict__ kh, bf16* __restrict__ vT,
    float* __restrict__ outp)
{
    __shared__ __align__(16) bf16 As[BM * BK];
    __shared__ __align__(16) bf16 Bs[BN * BK];
    const int tid = threadIdx.x;
    const int lane = tid & 63, wv = tid >> 6;
    const int g = lane >> 4, l15 = lane & 15;
    const int wr = wv >> 1, wc = wv & 1;
    const int bm = blockIdx.y * BM, bn = blockIdx.x * BN;

    f32x4 zero4 = {0.f, 0.f, 0.f, 0.f};
    f32x4 acc[4][4];
#pragma unroll
    for (int mi = 0; mi < 4; mi++)
#pragma unroll
        for (int ni = 0; ni < 4; ni++) acc[mi][ni] = zero4;

    const int r0 = wv * 32 + (lane >> 2);
    const int c0 = (lane & 3) * 8;
    const bf16* Ag0 = A + (size_t)(bm + r0) * K + c0;
    const bf16* Ag1 = Ag0 + (size_t)16 * K;
    const bf16* Bg0 = B + (size_t)(bn + r0) * K + c0;
    const bf16* Bg1 = Bg0 + (size_t)16 * K;
    bf16* AsW = &As[(wv * 32) * BK];
    bf16* BsW = &Bs[(wv * 32) * BK];

    for (int k0 = 0; k0 < K; k0 += BK) {
        gload16(Ag0 + k0, AsW);
        gload16(Ag1 + k0, AsW + 16 * BK);
        gload16(Bg0 + k0, BsW);
        gload16(Bg1 + k0, BsW + 16 * BK);
        __syncthreads();

        bf16x8 aF[4], bF[4];
#pragma unroll
        for (int mi = 0; mi < 4; mi++)
            aF[mi] = *(const bf16x8*)&As[(wr * 64 + mi * 16 + l15) * BK + g * 8];
#pragma unroll
        for (int ni = 0; ni < 4; ni++)
            bF[ni] = *(const bf16x8*)&Bs[(wc * 64 + ni * 16 + l15) * BK + g * 8];
#pragma unroll
        for (int mi = 0; mi < 4; mi++)
#pragma unroll
            for (int ni = 0; ni < 4; ni++)
                acc[mi][ni] = __builtin_amdgcn_mfma_f32_16x16x32_bf16(
                    aF[mi], bF[ni], acc[mi][ni], 0, 0, 0);
        __syncthreads();
    }

    if (mode == 0) {
#pragma unroll
        for (int ni = 0; ni < 4; ni++) {
            int n = bn + wc * 64 + ni * 16 + l15;       // 0..3071
            int which = n >> 10;                         // 0=q 1=k 2=v
            int c = n & 1023;
            int nh = c >> 6, d = c & 63;
            const float* bias_p = (which == 0) ? bq : (which == 1) ? bk : bv;
            float bias = bias_p[c];
            float scl = (which == 0) ? 0.125f : 1.0f;
#pragma unroll
            for (int mi = 0; mi < 4; mi++) {
#pragma unroll
                for (int r = 0; r < 4; r++) {
                    int m = bm + wr * 64 + mi * 16 + g * 4 + r;  // token
                    int s = m >> 1, b = m & 1;
                    int head = b * NHEAD + nh;
                    bf16 val = (bf16)((acc[mi][ni][r] + bias) * scl);
                    if (which == 2)
                        vT[((size_t)(head * HDIM + d)) * S_LEN + s] = val;
                    else {
                        bf16* dst = (which == 0) ? qh : kh;
                        dst[((size_t)(head * S_LEN + s)) * HDIM + d] = val;
                    }
                }
            }
        }
    } else {
#pragma unroll
        for (int ni = 0; ni < 4; ni++) {
            int n = bn + wc * 64 + ni * 16 + l15;
            float bias = bo[n];
#pragma unroll
            for (int mi = 0; mi < 4; mi++) {
#pragma unroll
                for (int r = 0; r < 4; r++) {
                    int m = bm + wr * 64 + mi * 16 + g * 4 + r;
                    outp[(size_t)m * HID + n] = acc[mi][ni][r] + bias;
                }
            }
        }
    }
}

// ---------------- flash attention, isolation-bitmask template ----------------
// VAR bits: 1=MASK (DMA+read+add+kmask), 2=QK (K loads+MFMA), 4=SM (softmax),
//           8=P (LDS roundtrip), 16=PV (V loads+MFMA).  31 = full (real output).
// Barrier-free; per-wave-PRIVATE mask double-buffer (race-free by in-order vmcnt:
// iter-t DMA is older than iter-t+1 K loads, so QK's K-wait implies DMA landed).
template<int VAR>
__global__ __launch_bounds__(256, 3) void attn(
    const bf16* __restrict__ q, const bf16* __restrict__ k, const bf16* __restrict__ vT,
    const float* __restrict__ amask,   // [16][2048][2048]
    const float* __restrict__ kmask,   // [32][2048]
    bf16* __restrict__ ctx)            // [4096][1024]
{
    constexpr bool M_ = VAR & 1, QK_ = VAR & 2, SM_ = VAR & 4, P_ = VAR & 8, PV_ = VAR & 16;

    __shared__ __align__(16) float MT[4][2][16 * 64];  // per-wave private dbuf (32 KB)
    __shared__ __align__(16) bf16 P[4][16][72];        // per-wave P tile (9.2 KB)

    const int tid = threadIdx.x, lane = tid & 63, wv = tid >> 6;
    const int g = lane >> 4, l15 = lane & 15;
    const int b = wv >> 1, stsub = wv & 1;

    // XCD swizzle: each XCD owns 2 heads -> K/V L2-resident
    const int hw = blockIdx.y * 64 + blockIdx.x;     // grid (64, 16)
    const int vid = (hw & 7) * 128 + (hw >> 3);
    const int nh = vid >> 6;
    const int st0 = (vid & 63) * 32;
    const int st0s = st0 + stsub * 16;               // wave q-base (16 rows)
    const int n = b * NHEAD + nh;

    const bf16* qrow = q + ((size_t)(n * S_LEN + st0s + l15)) * HDIM;
    bf16x8 bQ0 = *(const bf16x8*)(qrow + g * 8);
    bf16x8 bQ1 = *(const bf16x8*)(qrow + 32 + g * 8);

    // mask DMA addressing: [16 rows][16 chunks f32x4], logical chunk c of row r at
    // phys c^(r&7); inverse on global source. instr j covers rows 4j..4j+3.
    const int lrow = lane >> 4;
    const int ch0 = (lane & 15) ^ lrow;
    const float* msrcE = amask + ((size_t)nh * S_LEN + st0s + lrow) * S_LEN + 4 * ch0;
    const float* msrcO = amask + ((size_t)nh * S_LEN + st0s + lrow) * S_LEN + 4 * (ch0 ^ 4);
    float* mt0 = &MT[wv][0][0];
    float* mt1 = &MT[wv][1][0];

    f32x4 zero4 = {0.f, 0.f, 0.f, 0.f};
    f32x4 O[4];
#pragma unroll
    for (int t = 0; t < 4; t++) O[t] = zero4;
    float mrun = -1e30f, lrun = 0.f;                 // per-lane row q = l15

    const bf16* kbase = k + ((size_t)n * S_LEN + l15) * HDIM + g * 8;
    const bf16* vbase = vT + ((size_t)n * HDIM + l15) * S_LEN + g * 8;
    const float* kmb = kmask + (size_t)n * S_LEN + 4 * g;

    if (M_) {      // prologue: stage tile 0 into buf0 (private)
        gload16(msrcE,              mt0);
        gload16(msrcO + 4  * S_LEN, mt0 + 256);
        gload16(msrcE + 8  * S_LEN, mt0 + 512);
        gload16(msrcO + 12 * S_LEN, mt0 + 768);
    }

#pragma unroll 1
    for (int it = 0; it < 32; ++it) {
        const int tt = it * 64;
        const float* tile = (it & 1) ? mt1 : mt0;
        float* ntile      = (it & 1) ? mt0 : mt1;

        // 1. K + kmask register loads
        f32x4 km[4];
        bf16x8 aK[4][2];
        if (QK_ || M_) {
#pragma unroll
            for (int c = 0; c < 4; c++) {
                if (M_) km[c] = *(const f32x4*)(kmb + tt + 16 * c);
                if (QK_) {
                    const bf16* kp = kbase + (size_t)(tt + 16 * c) * HDIM;
                    aK[c][0] = *(const bf16x8*)kp;
                    aK[c][1] = *(const bf16x8*)(kp + 32);
                }
            }
        }
        // 2. QK^T (swapped): sc[c][r] = score(q=l15, k=tt+16c+4g+r)
        f32x4 sc[4];
#pragma unroll
        for (int c = 0; c < 4; c++) {
            if (QK_) {
                f32x4 s = zero4;
                s = __builtin_amdgcn_mfma_f32_16x16x32_bf16(aK[c][0], bQ0, s, 0, 0, 0);
                s = __builtin_amdgcn_mfma_f32_16x16x32_bf16(aK[c][1], bQ1, s, 0, 0, 0);
                sc[c] = s;
            } else {   // synthetic scores derived from live regs (not DCE-able)
                sc[c][0] = (float)bQ0[c] * 0.001f; sc[c][1] = (float)bQ0[c + 4] * 0.001f;
                sc[c][2] = (float)bQ1[c] * 0.001f; sc[c][3] = (float)bQ1[c + 4] * 0.001f;
            }
        }
        // 3. V loads (early, consumed after softmax)
        bf16x8 bV[4][2];
        if (PV_) {
#pragma unroll
            for (int dt = 0; dt < 4; dt++) {
                const bf16* vp = vbase + (size_t)(dt * 16) * S_LEN + tt;
                bV[dt][0] = *(const bf16x8*)vp;
                bV[dt][1] = *(const bf16x8*)(vp + 32);
            }
        }
        // 4. mask add (swizzled private LDS) + kmask
        if (M_) {
#pragma unroll
            for (int c = 0; c < 4; c++) {
                int phys = (4 * c + g) ^ (l15 & 7);
                f32x4 mk = *(const f32x4*)&tile[l15 * 64 + 4 * phys];
                sc[c] += mk + km[c];
            }
        }
        // 5. DMA next tile (youngest vmem of the iter; private buffer)
        if (M_ && it < 31) {
            gload16(msrcE + tt + 64,              ntile);
            gload16(msrcO + tt + 64 + 4  * S_LEN, ntile + 256);
            gload16(msrcE + tt + 64 + 8  * S_LEN, ntile + 512);
            gload16(msrcO + tt + 64 + 12 * S_LEN, ntile + 768);
        }
        // 6. online softmax
        if (SM_) {
            float cm = fmaxf(fmaxf(fmaxf(sc[0][0], sc[0][1]), fmaxf(sc[0][2], sc[0][3])),
                             fmaxf(fmaxf(sc[1][0], sc[1][1]), fmaxf(sc[1][2], sc[1][3])));
            cm = fmaxf(cm, fmaxf(fmaxf(fmaxf(sc[2][0], sc[2][1]), fmaxf(sc[2][2], sc[2][3])),
                                 fmaxf(fmaxf(sc[3][0], sc[3][1]), fmaxf(sc[3][2], sc[3][3]))));
            cm = fmaxf(cm, __shfl_xor(cm, 16, 64));
            cm = fmaxf(cm, __shfl_xor(cm, 32, 64));
            if (!__all(cm - mrun <= 8.0f)) {             // defer-max (T13)
                float mn = fmaxf(mrun, cm);
                float f = __expf(mrun - mn);
                mrun = mn;
                lrun *= f;
#pragma unroll
                for (int r = 0; r < 4; r++) {
                    float fb = __shfl(f, 4 * g + r, 64);
#pragma unroll
                    for (int dt = 0; dt < 4; dt++) O[dt][r] *= fb;
                }
            }
            float rs = 0.f;
#pragma unroll
            for (int c = 0; c < 4; c++)
#pragma unroll
                for (int r = 0; r < 4; r++) {
                    float p = __expf(sc[c][r] - mrun);
                    sc[c][r] = p;
                    rs += p;
                }
            rs += __shfl_xor(rs, 16, 64);
            rs += __shfl_xor(rs, 32, 64);
            lrun += rs;
        } else {
            lrun += 1.0f;
        }
        // 7. P -> per-wave LDS roundtrip
        bf16x8 aP0 = bQ0, aP1 = bQ1;
        if (P_) {
#pragma unroll
            for (int c = 0; c < 4; c++) {
                bf16x4 pk;
                pk[0] = (bf16)sc[c][0]; pk[1] = (bf16)sc[c][1];
                pk[2] = (bf16)sc[c][2]; pk[3] = (bf16)sc[c][3];
                *(bf16x4*)&P[wv][l15][16 * c + 4 * g] = pk;
            }
            aP0 = *(const bf16x8*)&P[wv][l15][g * 8];
            aP1 = *(const bf16x8*)&P[wv][l15][32 + g * 8];
        }
        // 8. PV
        if (PV_) {
#pragma unroll
            for (int dt = 0; dt < 4; dt++) {
                O[dt] = __builtin_amdgcn_mfma_f32_16x16x32_bf16(aP0, bV[dt][0], O[dt], 0, 0, 0);
                O[dt] = __builtin_amdgcn_mfma_f32_16x16x32_bf16(aP1, bV[dt][1], O[dt], 0, 0, 0);
            }
        }
        // liveness anchors (rule 17): keep sc/aP chains + the loop un-deletable
        asm volatile("" :: "v"(sc[0][0]), "v"(sc[1][1]), "v"(sc[2][2]), "v"(sc[3][3]),
                           "v"((float)aP0[0]), "v"((float)aP1[7]));
        asm volatile("" : "+v"(lrun));
    }

    // ---- epilogue ----
#pragma unroll
    for (int r = 0; r < 4; r++) {
        float lq = __shfl(lrun, 4 * g + r, 64);
        float inv = 1.0f / lq;
        int s = st0s + 4 * g + r;
        int token = s * BATCH + b;
#pragma unroll
        for (int dt = 0; dt < 4; dt++) {
            int h = nh * HDIM + dt * 16 + l15;
            ctx[(size_t)token * HID + h] = (bf16)(O[dt][r] * inv);
        }
    }
}

extern "C" void kernel_launch(void* const* d_in, const int* in_sizes, int n_in,
                              void* d_out, int out_size, void* d_ws, size_t ws_size,
                              hipStream_t stream) {
    const float* hidden = (const float*)d_in[0];
    const float* amask  = (const float*)d_in[1];
    const float* kmask  = (const float*)d_in[2];
    const float* Wq = (const float*)d_in[3];
    const float* bq = (const float*)d_in[4];
    const float* Wk = (const float*)d_in[5];
    const float* bk = (const float*)d_in[6];
    const float* Wv = (const float*)d_in[7];
    const float* bv = (const float*)d_in[8];
    const float* Wo = (const float*)d_in[9];
    const float* bo = (const float*)d_in[10];
    float* out = (float*)d_out;

    char* ws = (char*)d_ws;
    bf16* Xb   = (bf16*)(ws);                       // 8 MB  [4096][1024]
    bf16* Wcat = (bf16*)(ws + (8u  << 20));         // 6 MB  [3072][1024]
    bf16* Wob  = (bf16*)(ws + (14u << 20));         // 2 MB  [1024][1024]
    bf16* qh   = (bf16*)(ws + (16u << 20));         // 8 MB  [32][2048][64]
    bf16* kh   = (bf16*)(ws + (24u << 20));         // 8 MB
    bf16* vT   = (bf16*)(ws + (40u << 20));         // 8 MB  [32][64][2048]
    bf16* ctx  = (bf16*)(ws + (48u << 20));         // 8 MB  [4096][1024]

    cvt_f32_bf16<<<2048, 256, 0, stream>>>(hidden, Xb, NTOK * HID);
    cvt_f32_bf16<<<512, 256, 0, stream>>>(Wq, Wcat,              HID * HID);
    cvt_f32_bf16<<<512, 256, 0, stream>>>(Wk, Wcat + HID * HID,  HID * HID);
    cvt_f32_bf16<<<512, 256, 0, stream>>>(Wv, Wcat + 2 * HID * HID, HID * HID);
    cvt_f32_bf16<<<512, 256, 0, stream>>>(Wo, Wob, HID * HID);

    gemm_bt<<<dim3(24, 32), 256, 0, stream>>>(Xb, Wcat, NTOK, 3 * HID, HID, 0,
                                              bq, bk, bv, bo, qh, kh, vT, nullptr);

    // ---- isolation probes (ctx overwritten by the final full run) ----
    attn<0 ><<<dim3(64, 16), 256, 0, stream>>>(qh, kh, vT, amask, kmask, ctx); // empty loop
    attn<1 ><<<dim3(64, 16), 256, 0, stream>>>(qh, kh, vT, amask, kmask, ctx); // mask only
    attn<2 ><<<dim3(64, 16), 256, 0, stream>>>(qh, kh, vT, amask, kmask, ctx); // K/QK only
    attn<4 ><<<dim3(64, 16), 256, 0, stream>>>(qh, kh, vT, amask, kmask, ctx); // softmax only
    attn<24><<<dim3(64, 16), 256, 0, stream>>>(qh, kh, vT, amask, kmask, ctx); // P+PV only

    // ---- the real attention (last) ----
    attn<31><<<dim3(64, 16), 256, 0, stream>>>(qh, kh, vT, amask, kmask, ctx);

    gemm_bt<<<dim3(8, 32), 256, 0, stream>>>(ctx, Wob, NTOK, HID, HID, 1,
                                             bq, bk, bv, bo, qh, kh, vT, out);
}

// Round 11
// 471.021 us; speedup vs baseline: 1.5289x; 1.5289x over previous
//
#include <hip/hip_runtime.h>
#include <hip/hip_bf16.h>
#include <math.h>

#define S_LEN 2048
#define BATCH 2
#define HID 1024
#define NHEAD 16
#define HDIM 64
#define NTOK (S_LEN*BATCH)   // 4096

typedef __bf16 bf16;
typedef __bf16 bf16x4 __attribute__((ext_vector_type(4)));
typedef __bf16 bf16x8 __attribute__((ext_vector_type(8)));
typedef float f32x4 __attribute__((ext_vector_type(4)));

typedef const __attribute__((address_space(1))) unsigned int* gptr_t;
typedef __attribute__((address_space(3))) unsigned int* lptr_t;

__device__ __forceinline__ void gload16(const void* g, void* l) {
    __builtin_amdgcn_global_load_lds((gptr_t)g, (lptr_t)l, 16, 0, 0);
}

// ---------------- fp32 -> bf16 convert (8 elems/thread) ----------------
__global__ void cvt_f32_bf16(const float* __restrict__ src, bf16* __restrict__ dst, int n) {
    int i = (blockIdx.x * blockDim.x + threadIdx.x) * 8;
    if (i >= n) return;
    const float4* s = (const float4*)(src + i);
    float4 a = s[0], b = s[1];
    bf16x8 o;
    o[0] = (bf16)a.x; o[1] = (bf16)a.y; o[2] = (bf16)a.z; o[3] = (bf16)a.w;
    o[4] = (bf16)b.x; o[5] = (bf16)b.y; o[6] = (bf16)b.z; o[7] = (bf16)b.w;
    *(bf16x8*)(dst + i) = o;
}

// ---------------- mask tilize: fp32 [16][2048][2048] -> bf16 tiles ----------------
// tiles[nh][qt(64)][kc(32)]: tile = [32 q][72 k] bf16 (2304 elems, 4608 B; cols 64-71 pad).
// Pure streaming, no dependent chains: 8 independent load->cvt->store per thread.
__global__ __launch_bounds__(256) void mask_tilize(
    const float* __restrict__ amask, bf16* __restrict__ tiles)
{
    const int tid = threadIdx.x;
    const int nh = blockIdx.z, qt = blockIdx.y;
    const float* inq = amask + (size_t)nh * S_LEN * S_LEN + (size_t)(qt * 32) * S_LEN;
#pragma unroll
    for (int j = 0; j < 4; ++j) {
        int kc = blockIdx.x * 4 + j;
        bf16* outb = tiles + ((size_t)((nh * 64 + qt) * 32 + kc)) * 2304;
        const float* inb = inq + kc * 64;
#pragma unroll
        for (int half = 0; half < 2; ++half) {
            int v = half * 256 + tid;          // vec4 index 0..511
            int qq = v >> 4, kv = v & 15;      // q 0..31, k-vec 0..15
            float4 x = *(const float4*)(inb + (size_t)qq * S_LEN + kv * 4);
            bf16x4 y;
            y[0] = (bf16)x.x; y[1] = (bf16)x.y; y[2] = (bf16)x.z; y[3] = (bf16)x.w;
            *(bf16x4*)(outb + qq * 72 + kv * 4) = y;
        }
    }
}

// ---------------- GEMM: C[M][N] = A[M][K] * B[N][K]^T ----------------
#define BM 128
#define BN 128
#define BK 32

__global__ __launch_bounds__(256) void gemm_bt(
    const bf16* __restrict__ A, const bf16* __restrict__ B,
    int M, int N, int K, int mode,
    const float* __restrict__ bq, const float* __restrict__ bk,
    const float* __restrict__ bv, const float* __restrict__ bo,
    bf16* __restrict__ qh, bf16* __restrict__ kh, bf16* __restrict__ vT,
    float* __restrict__ outp)
{
    __shared__ __align__(16) bf16 As[BM * BK];
    __shared__ __align__(16) bf16 Bs[BN * BK];
    const int tid = threadIdx.x;
    const int lane = tid & 63, wv = tid >> 6;
    const int g = lane >> 4, l15 = lane & 15;
    const int wr = wv >> 1, wc = wv & 1;
    const int bm = blockIdx.y * BM, bn = blockIdx.x * BN;

    f32x4 zero4 = {0.f, 0.f, 0.f, 0.f};
    f32x4 acc[4][4];
#pragma unroll
    for (int mi = 0; mi < 4; mi++)
#pragma unroll
        for (int ni = 0; ni < 4; ni++) acc[mi][ni] = zero4;

    const int r0 = wv * 32 + (lane >> 2);
    const int c0 = (lane & 3) * 8;
    const bf16* Ag0 = A + (size_t)(bm + r0) * K + c0;
    const bf16* Ag1 = Ag0 + (size_t)16 * K;
    const bf16* Bg0 = B + (size_t)(bn + r0) * K + c0;
    const bf16* Bg1 = Bg0 + (size_t)16 * K;
    bf16* AsW = &As[(wv * 32) * BK];
    bf16* BsW = &Bs[(wv * 32) * BK];

    for (int k0 = 0; k0 < K; k0 += BK) {
        gload16(Ag0 + k0, AsW);
        gload16(Ag1 + k0, AsW + 16 * BK);
        gload16(Bg0 + k0, BsW);
        gload16(Bg1 + k0, BsW + 16 * BK);
        __syncthreads();

        bf16x8 aF[4], bF[4];
#pragma unroll
        for (int mi = 0; mi < 4; mi++)
            aF[mi] = *(const bf16x8*)&As[(wr * 64 + mi * 16 + l15) * BK + g * 8];
#pragma unroll
        for (int ni = 0; ni < 4; ni++)
            bF[ni] = *(const bf16x8*)&Bs[(wc * 64 + ni * 16 + l15) * BK + g * 8];
#pragma unroll
        for (int mi = 0; mi < 4; mi++)
#pragma unroll
            for (int ni = 0; ni < 4; ni++)
                acc[mi][ni] = __builtin_amdgcn_mfma_f32_16x16x32_bf16(
                    aF[mi], bF[ni], acc[mi][ni], 0, 0, 0);
        __syncthreads();
    }

    if (mode == 0) {
#pragma unroll
        for (int ni = 0; ni < 4; ni++) {
            int n = bn + wc * 64 + ni * 16 + l15;       // 0..3071
            int which = n >> 10;                         // 0=q 1=k 2=v
            int c = n & 1023;
            int nh = c >> 6, d = c & 63;
            const float* bias_p = (which == 0) ? bq : (which == 1) ? bk : bv;
            float bias = bias_p[c];
            float scl = (which == 0) ? 0.125f : 1.0f;
#pragma unroll
            for (int mi = 0; mi < 4; mi++) {
#pragma unroll
                for (int r = 0; r < 4; r++) {
                    int m = bm + wr * 64 + mi * 16 + g * 4 + r;  // token
                    int s = m >> 1, b = m & 1;
                    int head = b * NHEAD + nh;
                    bf16 val = (bf16)((acc[mi][ni][r] + bias) * scl);
                    if (which == 2)
                        vT[((size_t)(head * HDIM + d)) * S_LEN + s] = val;
                    else {
                        bf16* dst = (which == 0) ? qh : kh;
                        dst[((size_t)(head * S_LEN + s)) * HDIM + d] = val;
                    }
                }
            }
        }
    } else {
#pragma unroll
        for (int ni = 0; ni < 4; ni++) {
            int n = bn + wc * 64 + ni * 16 + l15;
            float bias = bo[n];
#pragma unroll
            for (int mi = 0; mi < 4; mi++) {
#pragma unroll
                for (int r = 0; r < 4; r++) {
                    int m = bm + wr * 64 + mi * 16 + g * 4 + r;
                    outp[(size_t)m * HID + n] = acc[mi][ni][r] + bias;
                }
            }
        }
    }
}

// ---------------- flash attention: barrier-free, private dbuf, tiled bf16 mask ----------------
// grid 1024 blocks x 4 waves; wave (b, stsub) fully independent, 16 q-rows, 32 iters x 64 keys.
// Mask from pre-tilized bf16 tiles: per wave-iter 3 contiguous 1KB global_load_lds into a
// private double buffer (race-free: in-order vmcnt, refill is youngest op of each iter).
__global__ __launch_bounds__(256, 4) void attn(
    const bf16* __restrict__ q, const bf16* __restrict__ k, const bf16* __restrict__ vT,
    const bf16* __restrict__ tiles,    // [16][64][32][32][72] bf16
    const float* __restrict__ kmask,   // [32][2048]
    bf16* __restrict__ ctx)            // [4096][1024]
{
    __shared__ __align__(16) bf16 MT[4][2][1536];  // per-wave private dbuf (24 KB; 1152 used)
    __shared__ __align__(16) bf16 P[4][16][72];    // per-wave P tile (9.2 KB)

    const int tid = threadIdx.x, lane = tid & 63, wv = tid >> 6;
    const int g = lane >> 4, l15 = lane & 15;
    const int b = wv >> 1, stsub = wv & 1;

    // XCD swizzle: each XCD owns 2 heads -> K/V L2-resident
    const int hw = blockIdx.y * 64 + blockIdx.x;     // grid (64, 16)
    const int vid = (hw & 7) * 128 + (hw >> 3);
    const int nh = vid >> 6;
    const int qt = vid & 63;
    const int st0s = qt * 32 + stsub * 16;           // wave q-base (16 rows)
    const int n = b * NHEAD + nh;

    const bf16* qrow = q + ((size_t)(n * S_LEN + st0s + l15)) * HDIM;
    bf16x8 bQ0 = *(const bf16x8*)(qrow + g * 8);
    bf16x8 bQ1 = *(const bf16x8*)(qrow + 32 + g * 8);

    // wave's mask half-tile source: rows [stsub*16, +16) = elems [stsub*1152, +1152) of each tile
    const bf16* twave = tiles + ((size_t)(nh * 64 + qt) * 32) * 2304 + stsub * 1152
                        + lane * 8;                  // + per-lane 16B
    bf16* mt0 = &MT[wv][0][0];
    bf16* mt1 = &MT[wv][1][0];

    f32x4 zero4 = {0.f, 0.f, 0.f, 0.f};
    f32x4 O[4];
#pragma unroll
    for (int t = 0; t < 4; t++) O[t] = zero4;
    float mrun = -1e30f, lrun = 0.f;                 // per-lane row q = l15

    const bf16* kbase = k + ((size_t)n * S_LEN + l15) * HDIM + g * 8;
    const bf16* vbase = vT + ((size_t)n * HDIM + l15) * S_LEN + g * 8;
    const float* kmb = kmask + (size_t)n * S_LEN + 4 * g;

    // prologue: stage tile 0 into buf0 (3 x 1KB contiguous)
    gload16(twave,        mt0);
    gload16(twave + 512,  mt0 + 512);
    gload16(twave + 1024, mt0 + 1024);

#pragma unroll 1
    for (int it = 0; it < 32; ++it) {
        const int tt = it * 64;
        const bf16* tile = (it & 1) ? mt1 : mt0;
        bf16* ntile      = (it & 1) ? mt0 : mt1;

        // 1. K + kmask register loads (oldest vmem of this iter)
        f32x4 km[4];
        bf16x8 aK[4][2];
#pragma unroll
        for (int c = 0; c < 4; c++) {
            km[c] = *(const f32x4*)(kmb + tt + 16 * c);
            const bf16* kp = kbase + (size_t)(tt + 16 * c) * HDIM;
            aK[c][0] = *(const bf16x8*)kp;
            aK[c][1] = *(const bf16x8*)(kp + 32);
        }
        // 2. QK^T (swapped): sc[c][r] = score(q=l15, k=tt+16c+4g+r)
        f32x4 sc[4];
#pragma unroll
        for (int c = 0; c < 4; c++) {
            f32x4 s = zero4;
            s = __builtin_amdgcn_mfma_f32_16x16x32_bf16(aK[c][0], bQ0, s, 0, 0, 0);
            s = __builtin_amdgcn_mfma_f32_16x16x32_bf16(aK[c][1], bQ1, s, 0, 0, 0);
            sc[c] = s;
        }
        // 3. V loads (consumed after softmax; older than the refill below)
        bf16x8 bV[4][2];
#pragma unroll
        for (int dt = 0; dt < 4; dt++) {
            const bf16* vp = vbase + (size_t)(dt * 16) * S_LEN + tt;
            bV[dt][0] = *(const bf16x8*)vp;
            bV[dt][1] = *(const bf16x8*)(vp + 32);
        }
        // 4. mask add: row l15, cols 16c+4g (+0..3); stride 72 -> 2-way bank alias (free)
#pragma unroll
        for (int c = 0; c < 4; c++) {
            bf16x4 mk = *(const bf16x4*)&tile[l15 * 72 + 16 * c + 4 * g];
            f32x4 mkf;
            mkf[0] = (float)mk[0]; mkf[1] = (float)mk[1];
            mkf[2] = (float)mk[2]; mkf[3] = (float)mk[3];
            sc[c] += mkf + km[c];
        }
        // 5. refill next tile (youngest vmem of the iter; other private buffer)
        if (it < 31) {
            const bf16* tsrc = twave + (size_t)(it + 1) * 2304;
            gload16(tsrc,        ntile);
            gload16(tsrc + 512,  ntile + 512);
            gload16(tsrc + 1024, ntile + 1024);
        }
        // 6. online softmax (per-lane row q = l15)
        float cm = fmaxf(fmaxf(fmaxf(sc[0][0], sc[0][1]), fmaxf(sc[0][2], sc[0][3])),
                         fmaxf(fmaxf(sc[1][0], sc[1][1]), fmaxf(sc[1][2], sc[1][3])));
        cm = fmaxf(cm, fmaxf(fmaxf(fmaxf(sc[2][0], sc[2][1]), fmaxf(sc[2][2], sc[2][3])),
                             fmaxf(fmaxf(sc[3][0], sc[3][1]), fmaxf(sc[3][2], sc[3][3]))));
        cm = fmaxf(cm, __shfl_xor(cm, 16, 64));
        cm = fmaxf(cm, __shfl_xor(cm, 32, 64));
        if (!__all(cm - mrun <= 8.0f)) {             // defer-max (T13)
            float mn = fmaxf(mrun, cm);
            float f = __expf(mrun - mn);
            mrun = mn;
            lrun *= f;
#pragma unroll
            for (int r = 0; r < 4; r++) {
                float fb = __shfl(f, 4 * g + r, 64);
#pragma unroll
                for (int dt = 0; dt < 4; dt++) O[dt][r] *= fb;
            }
        }
        float rs = 0.f;
#pragma unroll
        for (int c = 0; c < 4; c++)
#pragma unroll
            for (int r = 0; r < 4; r++) {
                float p = __expf(sc[c][r] - mrun);
                sc[c][r] = p;
                rs += p;
            }
        rs += __shfl_xor(rs, 16, 64);
        rs += __shfl_xor(rs, 32, 64);
        lrun += rs;
        // 7. P -> per-wave LDS roundtrip (compiler inserts lgkm waits)
#pragma unroll
        for (int c = 0; c < 4; c++) {
            bf16x4 pk;
            pk[0] = (bf16)sc[c][0]; pk[1] = (bf16)sc[c][1];
            pk[2] = (bf16)sc[c][2]; pk[3] = (bf16)sc[c][3];
            *(bf16x4*)&P[wv][l15][16 * c + 4 * g] = pk;
        }
        bf16x8 aP0 = *(const bf16x8*)&P[wv][l15][g * 8];
        bf16x8 aP1 = *(const bf16x8*)&P[wv][l15][32 + g * 8];
        // 8. PV (V-wait leaves the refill in flight: V is older)
#pragma unroll
        for (int dt = 0; dt < 4; dt++) {
            O[dt] = __builtin_amdgcn_mfma_f32_16x16x32_bf16(aP0, bV[dt][0], O[dt], 0, 0, 0);
            O[dt] = __builtin_amdgcn_mfma_f32_16x16x32_bf16(aP1, bV[dt][1], O[dt], 0, 0, 0);
        }
    }

    // ---- epilogue ----
#pragma unroll
    for (int r = 0; r < 4; r++) {
        float lq = __shfl(lrun, 4 * g + r, 64);
        float inv = 1.0f / lq;
        int s = st0s + 4 * g + r;
        int token = s * BATCH + b;
#pragma unroll
        for (int dt = 0; dt < 4; dt++) {
            int h = nh * HDIM + dt * 16 + l15;
            ctx[(size_t)token * HID + h] = (bf16)(O[dt][r] * inv);
        }
    }
}

extern "C" void kernel_launch(void* const* d_in, const int* in_sizes, int n_in,
                              void* d_out, int out_size, void* d_ws, size_t ws_size,
                              hipStream_t stream) {
    const float* hidden = (const float*)d_in[0];
    const float* amask  = (const float*)d_in[1];
    const float* kmask  = (const float*)d_in[2];
    const float* Wq = (const float*)d_in[3];
    const float* bq = (const float*)d_in[4];
    const float* Wk = (const float*)d_in[5];
    const float* bk = (const float*)d_in[6];
    const float* Wv = (const float*)d_in[7];
    const float* bv = (const float*)d_in[8];
    const float* Wo = (const float*)d_in[9];
    const float* bo = (const float*)d_in[10];
    float* out = (float*)d_out;

    char* ws = (char*)d_ws;
    bf16* Xb    = (bf16*)(ws);                       // 8 MB  [4096][1024]
    bf16* Wcat  = (bf16*)(ws + (8u  << 20));         // 6 MB  [3072][1024]
    bf16* Wob   = (bf16*)(ws + (14u << 20));         // 2 MB  [1024][1024]
    bf16* qh    = (bf16*)(ws + (16u << 20));         // 8 MB  [32][2048][64]
    bf16* kh    = (bf16*)(ws + (24u << 20));         // 8 MB
    bf16* vT    = (bf16*)(ws + (32u << 20));         // 8 MB  [32][64][2048]
    bf16* ctx   = (bf16*)(ws + (40u << 20));         // 8 MB  [4096][1024]
    bf16* tiles = (bf16*)(ws + (48u << 20));         // 151 MB tiled bf16 mask (+pad)

    cvt_f32_bf16<<<2048, 256, 0, stream>>>(hidden, Xb, NTOK * HID);
    cvt_f32_bf16<<<512, 256, 0, stream>>>(Wq, Wcat,              HID * HID);
    cvt_f32_bf16<<<512, 256, 0, stream>>>(Wk, Wcat + HID * HID,  HID * HID);
    cvt_f32_bf16<<<512, 256, 0, stream>>>(Wv, Wcat + 2 * HID * HID, HID * HID);
    cvt_f32_bf16<<<512, 256, 0, stream>>>(Wo, Wob, HID * HID);

    mask_tilize<<<dim3(8, 64, 16), 256, 0, stream>>>(amask, tiles);

    gemm_bt<<<dim3(24, 32), 256, 0, stream>>>(Xb, Wcat, NTOK, 3 * HID, HID, 0,
                                              bq, bk, bv, bo, qh, kh, vT, nullptr);
    attn<<<dim3(64, 16), 256, 0, stream>>>(qh, kh, vT, tiles, kmask, ctx);
    gemm_bt<<<dim3(8, 32), 256, 0, stream>>>(ctx, Wob, NTOK, HID, HID, 1,
                                             bq, bk, bv, bo, qh, kh, vT, out);
}

// Round 12
// 255.048 us; speedup vs baseline: 2.8236x; 1.8468x over previous
//
#include <hip/hip_runtime.h>
#include <hip/hip_bf16.h>
#include <math.h>

#define S_LEN 2048
#define BATCH 2
#define HID 1024
#define NHEAD 16
#define HDIM 64
#define NTOK (S_LEN*BATCH)   // 4096

typedef __bf16 bf16;
typedef __bf16 bf16x4 __attribute__((ext_vector_type(4)));
typedef __bf16 bf16x8 __attribute__((ext_vector_type(8)));
typedef float f32x4 __attribute__((ext_vector_type(4)));

typedef const __attribute__((address_space(1))) unsigned int* gptr_t;
typedef __attribute__((address_space(3))) unsigned int* lptr_t;

__device__ __forceinline__ void gload16(const void* g, void* l) {
    __builtin_amdgcn_global_load_lds((gptr_t)g, (lptr_t)l, 16, 0, 0);
}

// ---------------- fp32 -> bf16 convert (8 elems/thread) ----------------
__global__ void cvt_f32_bf16(const float* __restrict__ src, bf16* __restrict__ dst, int n) {
    int i = (blockIdx.x * blockDim.x + threadIdx.x) * 8;
    if (i >= n) return;
    const float4* s = (const float4*)(src + i);
    float4 a = s[0], b = s[1];
    bf16x8 o;
    o[0] = (bf16)a.x; o[1] = (bf16)a.y; o[2] = (bf16)a.z; o[3] = (bf16)a.w;
    o[4] = (bf16)b.x; o[5] = (bf16)b.y; o[6] = (bf16)b.z; o[7] = (bf16)b.w;
    *(bf16x8*)(dst + i) = o;
}

// ---------------- GEMM: C[M][N] = A[M][K] * B[N][K]^T ----------------
#define BM 128
#define BN 128
#define BK 32

__global__ __launch_bounds__(256) void gemm_bt(
    const bf16* __restrict__ A, const bf16* __restrict__ B,
    int M, int N, int K, int mode,
    const float* __restrict__ bq, const float* __restrict__ bk,
    const float* __restrict__ bv, const float* __restrict__ bo,
    bf16* __restrict__ qh, bf16* __restrict__ kh, bf16* __restrict__ vT,
    float* __restrict__ outp)
{
    __shared__ __align__(16) bf16 As[BM * BK];
    __shared__ __align__(16) bf16 Bs[BN * BK];
    const int tid = threadIdx.x;
    const int lane = tid & 63, wv = tid >> 6;
    const int g = lane >> 4, l15 = lane & 15;
    const int wr = wv >> 1, wc = wv & 1;
    const int bm = blockIdx.y * BM, bn = blockIdx.x * BN;

    f32x4 zero4 = {0.f, 0.f, 0.f, 0.f};
    f32x4 acc[4][4];
#pragma unroll
    for (int mi = 0; mi < 4; mi++)
#pragma unroll
        for (int ni = 0; ni < 4; ni++) acc[mi][ni] = zero4;

    const int r0 = wv * 32 + (lane >> 2);
    const int c0 = (lane & 3) * 8;
    const bf16* Ag0 = A + (size_t)(bm + r0) * K + c0;
    const bf16* Ag1 = Ag0 + (size_t)16 * K;
    const bf16* Bg0 = B + (size_t)(bn + r0) * K + c0;
    const bf16* Bg1 = Bg0 + (size_t)16 * K;
    bf16* AsW = &As[(wv * 32) * BK];
    bf16* BsW = &Bs[(wv * 32) * BK];

    for (int k0 = 0; k0 < K; k0 += BK) {
        gload16(Ag0 + k0, AsW);
        gload16(Ag1 + k0, AsW + 16 * BK);
        gload16(Bg0 + k0, BsW);
        gload16(Bg1 + k0, BsW + 16 * BK);
        __syncthreads();

        bf16x8 aF[4], bF[4];
#pragma unroll
        for (int mi = 0; mi < 4; mi++)
            aF[mi] = *(const bf16x8*)&As[(wr * 64 + mi * 16 + l15) * BK + g * 8];
#pragma unroll
        for (int ni = 0; ni < 4; ni++)
            bF[ni] = *(const bf16x8*)&Bs[(wc * 64 + ni * 16 + l15) * BK + g * 8];
#pragma unroll
        for (int mi = 0; mi < 4; mi++)
#pragma unroll
            for (int ni = 0; ni < 4; ni++)
                acc[mi][ni] = __builtin_amdgcn_mfma_f32_16x16x32_bf16(
                    aF[mi], bF[ni], acc[mi][ni], 0, 0, 0);
        __syncthreads();
    }

    if (mode == 0) {
#pragma unroll
        for (int ni = 0; ni < 4; ni++) {
            int n = bn + wc * 64 + ni * 16 + l15;       // 0..3071
            int which = n >> 10;                         // 0=q 1=k 2=v
            int c = n & 1023;
            int nh = c >> 6, d = c & 63;
            const float* bias_p = (which == 0) ? bq : (which == 1) ? bk : bv;
            float bias = bias_p[c];
            float scl = (which == 0) ? 0.125f : 1.0f;
#pragma unroll
            for (int mi = 0; mi < 4; mi++) {
#pragma unroll
                for (int r = 0; r < 4; r++) {
                    int m = bm + wr * 64 + mi * 16 + g * 4 + r;  // token
                    int s = m >> 1, b = m & 1;
                    int head = b * NHEAD + nh;
                    bf16 val = (bf16)((acc[mi][ni][r] + bias) * scl);
                    if (which == 2)
                        vT[((size_t)(head * HDIM + d)) * S_LEN + s] = val;
                    else {
                        bf16* dst = (which == 0) ? qh : kh;
                        dst[((size_t)(head * S_LEN + s)) * HDIM + d] = val;
                    }
                }
            }
        }
    } else {
#pragma unroll
        for (int ni = 0; ni < 4; ni++) {
            int n = bn + wc * 64 + ni * 16 + l15;
            float bias = bo[n];
#pragma unroll
            for (int mi = 0; mi < 4; mi++) {
#pragma unroll
                for (int r = 0; r < 4; r++) {
                    int m = bm + wr * 64 + mi * 16 + g * 4 + r;
                    outp[(size_t)m * HID + n] = acc[mi][ni][r] + bias;
                }
            }
        }
    }
}

// ---------------- flash attention, GEMM-shaped (m97 pattern) ----------------
// grid 1024 blocks x 4 waves; wave = (b, stsub); block q-tile 32 rows, 32 iters x 64 keys.
// Per iter: cooperative CONTIGUOUS global_load_lds staging of K[2][64][64], V[2][64][64],
// mask[32][64]f32, kmask[2][64]f32 (41 instrs/block, ~10/wave) -> barrier -> swizzled
// ds_read_b128 consumption + MFMA -> barrier. XOR swizzle applied on DMA source (rule 21).
__global__ __launch_bounds__(256) void attn(
    const bf16* __restrict__ q, const bf16* __restrict__ kh, const bf16* __restrict__ vT,
    const float* __restrict__ amask,   // [16][2048][2048]
    const float* __restrict__ kmask,   // [32][2048]
    bf16* __restrict__ ctx)            // [4096][1024]
{
    __shared__ __align__(16) bf16 KS[2][64 * 64];   // [b][key][d] swz   16 KB
    __shared__ __align__(16) bf16 VS[2][64 * 64];   // [b][d][key] swz   16 KB
    __shared__ __align__(16) float MS[32 * 64];     // [q][k] swz         8 KB
    __shared__ __align__(16) float KM[256];         // [b:16ch][k]        1 KB
    __shared__ __align__(16) bf16 P[4][16 * 72];    // per-wave P       9.2 KB

    const int tid = threadIdx.x, lane = tid & 63, wv = tid >> 6;
    const int g = lane >> 4, l15 = lane & 15;
    const int b = wv >> 1, stsub = wv & 1;

    // XCD swizzle: each XCD owns 2 heads
    const int hw = blockIdx.y * 64 + blockIdx.x;     // grid (64, 16)
    const int vid = (hw & 7) * 128 + (hw >> 3);
    const int nh = vid >> 6;
    const int qt = vid & 63;
    const int st0 = qt * 32;
    const int st0s = st0 + stsub * 16;               // wave q-base
    const int n = b * NHEAD + nh;

    const bf16* qrow = q + ((size_t)(n * S_LEN + st0s + l15)) * HDIM;
    bf16x8 bQ0 = *(const bf16x8*)(qrow + g * 8);
    bf16x8 bQ1 = *(const bf16x8*)(qrow + 32 + g * 8);

    // ---- staging addresses (tt-independent parts) ----
    // K/V: instr j covers 8 rows x 128B. lane -> row_local = lane>>3, phys8 = lane&7,
    // logical chunk = phys8 ^ (row&7)  (8j keeps row&7 invariant).
    const int krow = lane >> 3;
    const int kc8 = (lane & 7) ^ (krow & 7);
    // wave role: wv 0/1 -> K(b=wv); wv 2/3 -> V(b=wv-2)
    const int bsel = wv & 1;
    const bf16* kvsrc;
    size_t kvstride;
    if (wv < 2) {   // K: kh[n'][key][d]
        kvsrc = kh + ((size_t)(bsel * NHEAD + nh) * S_LEN + krow) * HDIM + kc8 * 8;
        kvstride = (size_t)8 * HDIM;     // 8 rows per instr step
    } else {        // V: vT[n'][d][s]
        kvsrc = vT + ((size_t)(bsel * NHEAD + nh) * HDIM + krow) * S_LEN + kc8 * 8;
        kvstride = (size_t)8 * S_LEN;
    }
    bf16* kvdst = (wv < 2) ? &KS[bsel][0] : &VS[bsel][0];
    // mask: each wave stages rows 8*wv..8*wv+7 (2 instrs of 4 rows x 256B)
    const int mrowA = 8 * wv + (lane >> 4);          // j=0 rows
    const int mrowB = mrowA + 4;                     // j=1 rows
    const int mcA = (lane & 15) ^ ((mrowA & 7) << 1);
    const int mcB = (lane & 15) ^ ((mrowB & 7) << 1);
    const float* msrcA = amask + ((size_t)nh * S_LEN + st0 + mrowA) * S_LEN + mcA * 4;
    const float* msrcB = amask + ((size_t)nh * S_LEN + st0 + mrowB) * S_LEN + mcB * 4;
    float* mdstA = MS + (8 * wv) * 64;
    float* mdstB = MS + (8 * wv + 4) * 64;
    // kmask (wave 0 only): lane -> chunk = lane (chunks 0-15: b0, 16-31: b1, rest pad)
    const int kmb_ = (lane >> 4) & 1;
    const float* kmsrc = kmask + (size_t)(kmb_ * NHEAD + nh) * S_LEN + (lane & 15) * 4;

    f32x4 zero4 = {0.f, 0.f, 0.f, 0.f};
    f32x4 O[4];
#pragma unroll
    for (int t = 0; t < 4; t++) O[t] = zero4;
    float mrun = -1e30f, lrun = 0.f;                 // per-lane row q = l15

    const int pk8 = l15 & 7;                          // read-side XOR key
    const int mr = stsub * 16 + l15;                  // mask row consumed

#pragma unroll 1
    for (int it = 0; it < 32; ++it) {
        const int tt = it * 64;
        // ---- cooperative staging (contiguous 1KB bursts) ----
#pragma unroll
        for (int j = 0; j < 8; ++j)
            gload16(kvsrc + tt * (wv < 2 ? HDIM : 1) + j * kvstride, kvdst + j * 512);
        gload16(msrcA + tt, mdstA);
        gload16(msrcB + tt, mdstB);
        if (wv == 0) gload16(kmsrc + tt, KM);
        __syncthreads();   // drains staging

        // ---- QK^T from LDS: aK[c][h] = K[key=16c+l15][d = g*8+32h] ----
        f32x4 sc[4];
#pragma unroll
        for (int c = 0; c < 4; c++) {
            bf16x8 aK0 = *(const bf16x8*)&KS[b][(16 * c + l15) * 64 + (g ^ pk8) * 8];
            bf16x8 aK1 = *(const bf16x8*)&KS[b][(16 * c + l15) * 64 + ((g + 4) ^ pk8) * 8];
            f32x4 s = zero4;
            s = __builtin_amdgcn_mfma_f32_16x16x32_bf16(aK0, bQ0, s, 0, 0, 0);
            s = __builtin_amdgcn_mfma_f32_16x16x32_bf16(aK1, bQ1, s, 0, 0, 0);
            sc[c] = s;
        }
        // ---- masks from LDS ----
#pragma unroll
        for (int c = 0; c < 4; c++) {
            int physm = (4 * c + g) ^ ((mr & 7) << 1);
            f32x4 mk = *(const f32x4*)&MS[mr * 64 + physm * 4];
            f32x4 km = *(const f32x4*)&KM[b * 64 + (4 * c + g) * 4];
            sc[c] += mk + km;
        }
        // ---- online softmax (per-lane row q = l15) ----
        float cm = fmaxf(fmaxf(fmaxf(sc[0][0], sc[0][1]), fmaxf(sc[0][2], sc[0][3])),
                         fmaxf(fmaxf(sc[1][0], sc[1][1]), fmaxf(sc[1][2], sc[1][3])));
        cm = fmaxf(cm, fmaxf(fmaxf(fmaxf(sc[2][0], sc[2][1]), fmaxf(sc[2][2], sc[2][3])),
                             fmaxf(fmaxf(sc[3][0], sc[3][1]), fmaxf(sc[3][2], sc[3][3]))));
        cm = fmaxf(cm, __shfl_xor(cm, 16, 64));
        cm = fmaxf(cm, __shfl_xor(cm, 32, 64));
        if (!__all(cm - mrun <= 8.0f)) {             // defer-max (T13)
            float mn = fmaxf(mrun, cm);
            float f = __expf(mrun - mn);
            mrun = mn;
            lrun *= f;
#pragma unroll
            for (int r = 0; r < 4; r++) {
                float fb = __shfl(f, 4 * g + r, 64);
#pragma unroll
                for (int dt = 0; dt < 4; dt++) O[dt][r] *= fb;
            }
        }
        float rs = 0.f;
#pragma unroll
        for (int c = 0; c < 4; c++)
#pragma unroll
            for (int r = 0; r < 4; r++) {
                float p = __expf(sc[c][r] - mrun);
                sc[c][r] = p;
                rs += p;
            }
        rs += __shfl_xor(rs, 16, 64);
        rs += __shfl_xor(rs, 32, 64);
        lrun += rs;
        // ---- P roundtrip (per-wave region; compiler inserts lgkm waits) ----
#pragma unroll
        for (int c = 0; c < 4; c++) {
            bf16x4 pk;
            pk[0] = (bf16)sc[c][0]; pk[1] = (bf16)sc[c][1];
            pk[2] = (bf16)sc[c][2]; pk[3] = (bf16)sc[c][3];
            *(bf16x4*)&P[wv][l15 * 72 + 16 * c + 4 * g] = pk;
        }
        bf16x8 aP0 = *(const bf16x8*)&P[wv][l15 * 72 + g * 8];
        bf16x8 aP1 = *(const bf16x8*)&P[wv][l15 * 72 + 32 + g * 8];
        // ---- PV from LDS: bV[dt][h] = V[k=g*8+32h][d=dt*16+l15] ----
#pragma unroll
        for (int dt = 0; dt < 4; dt++) {
            bf16x8 bV0 = *(const bf16x8*)&VS[b][(dt * 16 + l15) * 64 + (g ^ pk8) * 8];
            bf16x8 bV1 = *(const bf16x8*)&VS[b][(dt * 16 + l15) * 64 + ((g + 4) ^ pk8) * 8];
            O[dt] = __builtin_amdgcn_mfma_f32_16x16x32_bf16(aP0, bV0, O[dt], 0, 0, 0);
            O[dt] = __builtin_amdgcn_mfma_f32_16x16x32_bf16(aP1, bV1, O[dt], 0, 0, 0);
        }
        __syncthreads();   // all reads done before next stage overwrites
    }

    // ---- epilogue ----
#pragma unroll
    for (int r = 0; r < 4; r++) {
        float lq = __shfl(lrun, 4 * g + r, 64);
        float inv = 1.0f / lq;
        int s = st0s + 4 * g + r;
        int token = s * BATCH + b;
#pragma unroll
        for (int dt = 0; dt < 4; dt++) {
            int h = nh * HDIM + dt * 16 + l15;
            ctx[(size_t)token * HID + h] = (bf16)(O[dt][r] * inv);
        }
    }
}

extern "C" void kernel_launch(void* const* d_in, const int* in_sizes, int n_in,
                              void* d_out, int out_size, void* d_ws, size_t ws_size,
                              hipStream_t stream) {
    const float* hidden = (const float*)d_in[0];
    const float* amask  = (const float*)d_in[1];
    const float* kmask  = (const float*)d_in[2];
    const float* Wq = (const float*)d_in[3];
    const float* bq = (const float*)d_in[4];
    const float* Wk = (const float*)d_in[5];
    const float* bk = (const float*)d_in[6];
    const float* Wv = (const float*)d_in[7];
    const float* bv = (const float*)d_in[8];
    const float* Wo = (const float*)d_in[9];
    const float* bo = (const float*)d_in[10];
    float* out = (float*)d_out;

    char* ws = (char*)d_ws;
    bf16* Xb   = (bf16*)(ws);                       // 8 MB  [4096][1024]
    bf16* Wcat = (bf16*)(ws + (8u  << 20));         // 6 MB  [3072][1024]
    bf16* Wob  = (bf16*)(ws + (14u << 20));         // 2 MB  [1024][1024]
    bf16* qh   = (bf16*)(ws + (16u << 20));         // 8 MB  [32][2048][64]
    bf16* kh   = (bf16*)(ws + (24u << 20));         // 8 MB
    bf16* vT   = (bf16*)(ws + (32u << 20));         // 8 MB  [32][64][2048]
    bf16* ctx  = (bf16*)(ws + (40u << 20));         // 8 MB  [4096][1024]

    cvt_f32_bf16<<<2048, 256, 0, stream>>>(hidden, Xb, NTOK * HID);
    cvt_f32_bf16<<<512, 256, 0, stream>>>(Wq, Wcat,              HID * HID);
    cvt_f32_bf16<<<512, 256, 0, stream>>>(Wk, Wcat + HID * HID,  HID * HID);
    cvt_f32_bf16<<<512, 256, 0, stream>>>(Wv, Wcat + 2 * HID * HID, HID * HID);
    cvt_f32_bf16<<<512, 256, 0, stream>>>(Wo, Wob, HID * HID);

    gemm_bt<<<dim3(24, 32), 256, 0, stream>>>(Xb, Wcat, NTOK, 3 * HID, HID, 0,
                                              bq, bk, bv, bo, qh, kh, vT, nullptr);
    attn<<<dim3(64, 16), 256, 0, stream>>>(qh, kh, vT, amask, kmask, ctx);
    gemm_bt<<<dim3(8, 32), 256, 0, stream>>>(ctx, Wob, NTOK, HID, HID, 1,
                                             bq, bk, bv, bo, qh, kh, vT, out);
}

// Round 13
// 254.932 us; speedup vs baseline: 2.8249x; 1.0005x over previous
//
#include <hip/hip_runtime.h>
#include <hip/hip_bf16.h>
#include <math.h>

#define S_LEN 2048
#define BATCH 2
#define HID 1024
#define NHEAD 16
#define HDIM 64
#define NTOK (S_LEN*BATCH)   // 4096

typedef __bf16 bf16;
typedef __bf16 bf16x4 __attribute__((ext_vector_type(4)));
typedef __bf16 bf16x8 __attribute__((ext_vector_type(8)));
typedef float f32x4 __attribute__((ext_vector_type(4)));

typedef const __attribute__((address_space(1))) unsigned int* gptr_t;
typedef __attribute__((address_space(3))) unsigned int* lptr_t;

__device__ __forceinline__ void gload16(const void* g, void* l) {
    __builtin_amdgcn_global_load_lds((gptr_t)g, (lptr_t)l, 16, 0, 0);
}

// ---------------- fp32 -> bf16 convert (8 elems/thread) ----------------
__global__ void cvt_f32_bf16(const float* __restrict__ src, bf16* __restrict__ dst, int n) {
    int i = (blockIdx.x * blockDim.x + threadIdx.x) * 8;
    if (i >= n) return;
    const float4* s = (const float4*)(src + i);
    float4 a = s[0], b = s[1];
    bf16x8 o;
    o[0] = (bf16)a.x; o[1] = (bf16)a.y; o[2] = (bf16)a.z; o[3] = (bf16)a.w;
    o[4] = (bf16)b.x; o[5] = (bf16)b.y; o[6] = (bf16)b.z; o[7] = (bf16)b.w;
    *(bf16x8*)(dst + i) = o;
}

// ---------------- GEMM: C[M][N] = A[M][K] * B[N][K]^T ----------------
#define BM 128
#define BN 128
#define BK 32

__global__ __launch_bounds__(256) void gemm_bt(
    const bf16* __restrict__ A, const bf16* __restrict__ B,
    int M, int N, int K, int mode,
    const float* __restrict__ bq, const float* __restrict__ bk,
    const float* __restrict__ bv, const float* __restrict__ bo,
    bf16* __restrict__ qh, bf16* __restrict__ kh, bf16* __restrict__ vT,
    float* __restrict__ outp)
{
    __shared__ __align__(16) bf16 As[BM * BK];
    __shared__ __align__(16) bf16 Bs[BN * BK];
    const int tid = threadIdx.x;
    const int lane = tid & 63, wv = tid >> 6;
    const int g = lane >> 4, l15 = lane & 15;
    const int wr = wv >> 1, wc = wv & 1;
    const int bm = blockIdx.y * BM, bn = blockIdx.x * BN;

    f32x4 zero4 = {0.f, 0.f, 0.f, 0.f};
    f32x4 acc[4][4];
#pragma unroll
    for (int mi = 0; mi < 4; mi++)
#pragma unroll
        for (int ni = 0; ni < 4; ni++) acc[mi][ni] = zero4;

    const int r0 = wv * 32 + (lane >> 2);
    const int c0 = (lane & 3) * 8;
    const bf16* Ag0 = A + (size_t)(bm + r0) * K + c0;
    const bf16* Ag1 = Ag0 + (size_t)16 * K;
    const bf16* Bg0 = B + (size_t)(bn + r0) * K + c0;
    const bf16* Bg1 = Bg0 + (size_t)16 * K;
    bf16* AsW = &As[(wv * 32) * BK];
    bf16* BsW = &Bs[(wv * 32) * BK];

    for (int k0 = 0; k0 < K; k0 += BK) {
        gload16(Ag0 + k0, AsW);
        gload16(Ag1 + k0, AsW + 16 * BK);
        gload16(Bg0 + k0, BsW);
        gload16(Bg1 + k0, BsW + 16 * BK);
        __syncthreads();

        bf16x8 aF[4], bF[4];
#pragma unroll
        for (int mi = 0; mi < 4; mi++)
            aF[mi] = *(const bf16x8*)&As[(wr * 64 + mi * 16 + l15) * BK + g * 8];
#pragma unroll
        for (int ni = 0; ni < 4; ni++)
            bF[ni] = *(const bf16x8*)&Bs[(wc * 64 + ni * 16 + l15) * BK + g * 8];
#pragma unroll
        for (int mi = 0; mi < 4; mi++)
#pragma unroll
            for (int ni = 0; ni < 4; ni++)
                acc[mi][ni] = __builtin_amdgcn_mfma_f32_16x16x32_bf16(
                    aF[mi], bF[ni], acc[mi][ni], 0, 0, 0);
        __syncthreads();
    }

    if (mode == 0) {
#pragma unroll
        for (int ni = 0; ni < 4; ni++) {
            int n = bn + wc * 64 + ni * 16 + l15;       // 0..3071
            int which = n >> 10;                         // 0=q 1=k 2=v
            int c = n & 1023;
            int nh = c >> 6, d = c & 63;
            const float* bias_p = (which == 0) ? bq : (which == 1) ? bk : bv;
            float bias = bias_p[c];
            float scl = (which == 0) ? 0.125f : 1.0f;
#pragma unroll
            for (int mi = 0; mi < 4; mi++) {
#pragma unroll
                for (int r = 0; r < 4; r++) {
                    int m = bm + wr * 64 + mi * 16 + g * 4 + r;  // token
                    int s = m >> 1, b = m & 1;
                    int head = b * NHEAD + nh;
                    bf16 val = (bf16)((acc[mi][ni][r] + bias) * scl);
                    if (which == 2)
                        vT[((size_t)(head * HDIM + d)) * S_LEN + s] = val;
                    else {
                        bf16* dst = (which == 0) ? qh : kh;
                        dst[((size_t)(head * S_LEN + s)) * HDIM + d] = val;
                    }
                }
            }
        }
    } else {
#pragma unroll
        for (int ni = 0; ni < 4; ni++) {
            int n = bn + wc * 64 + ni * 16 + l15;
            float bias = bo[n];
#pragma unroll
            for (int mi = 0; mi < 4; mi++) {
#pragma unroll
                for (int r = 0; r < 4; r++) {
                    int m = bm + wr * 64 + mi * 16 + g * 4 + r;
                    outp[(size_t)m * HID + n] = acc[mi][ni][r] + bias;
                }
            }
        }
    }
}

// ---------------- flash attention, GEMM-shaped (m97 pattern) ----------------
// grid 1024 blocks x 4 waves; wave = (b, stsub); block q-tile 32 rows, 32 iters x 64 keys.
// Per iter: cooperative CONTIGUOUS global_load_lds staging of K[2][64][64], V[2][64][64],
// mask[32][64]f32, kmask[2][64]f32 (41 instrs/block, ~10/wave) -> barrier -> swizzled
// ds_read_b128 consumption + MFMA -> barrier. XOR swizzle applied on DMA source (rule 21).
__global__ __launch_bounds__(256) void attn(
    const bf16* __restrict__ q, const bf16* __restrict__ kh, const bf16* __restrict__ vT,
    const float* __restrict__ amask,   // [16][2048][2048]
    const float* __restrict__ kmask,   // [32][2048]
    bf16* __restrict__ ctx)            // [4096][1024]
{
    __shared__ __align__(16) bf16 KS[2][64 * 64];   // [b][key][d] swz   16 KB
    __shared__ __align__(16) bf16 VS[2][64 * 64];   // [b][d][key] swz   16 KB
    __shared__ __align__(16) float MS[32 * 64];     // [q][k] swz         8 KB
    __shared__ __align__(16) float KM[256];         // [b:16ch][k]        1 KB
    __shared__ __align__(16) bf16 P[4][16 * 72];    // per-wave P       9.2 KB

    const int tid = threadIdx.x, lane = tid & 63, wv = tid >> 6;
    const int g = lane >> 4, l15 = lane & 15;
    const int b = wv >> 1, stsub = wv & 1;

    // XCD swizzle: each XCD owns 2 heads
    const int hw = blockIdx.y * 64 + blockIdx.x;     // grid (64, 16)
    const int vid = (hw & 7) * 128 + (hw >> 3);
    const int nh = vid >> 6;
    const int qt = vid & 63;
    const int st0 = qt * 32;
    const int st0s = st0 + stsub * 16;               // wave q-base
    const int n = b * NHEAD + nh;

    const bf16* qrow = q + ((size_t)(n * S_LEN + st0s + l15)) * HDIM;
    bf16x8 bQ0 = *(const bf16x8*)(qrow + g * 8);
    bf16x8 bQ1 = *(const bf16x8*)(qrow + 32 + g * 8);

    // ---- staging addresses (tt-independent parts) ----
    // K/V: instr j covers 8 rows x 128B. lane -> row_local = lane>>3, phys8 = lane&7,
    // logical chunk = phys8 ^ (row&7)  (8j keeps row&7 invariant).
    const int krow = lane >> 3;
    const int kc8 = (lane & 7) ^ (krow & 7);
    // wave role: wv 0/1 -> K(b=wv); wv 2/3 -> V(b=wv-2)
    const int bsel = wv & 1;
    const bf16* kvsrc;
    size_t kvstride;
    if (wv < 2) {   // K: kh[n'][key][d]
        kvsrc = kh + ((size_t)(bsel * NHEAD + nh) * S_LEN + krow) * HDIM + kc8 * 8;
        kvstride = (size_t)8 * HDIM;     // 8 rows per instr step
    } else {        // V: vT[n'][d][s]
        kvsrc = vT + ((size_t)(bsel * NHEAD + nh) * HDIM + krow) * S_LEN + kc8 * 8;
        kvstride = (size_t)8 * S_LEN;
    }
    bf16* kvdst = (wv < 2) ? &KS[bsel][0] : &VS[bsel][0];
    // mask: each wave stages rows 8*wv..8*wv+7 (2 instrs of 4 rows x 256B)
    const int mrowA = 8 * wv + (lane >> 4);          // j=0 rows
    const int mrowB = mrowA + 4;                     // j=1 rows
    const int mcA = (lane & 15) ^ ((mrowA & 7) << 1);
    const int mcB = (lane & 15) ^ ((mrowB & 7) << 1);
    const float* msrcA = amask + ((size_t)nh * S_LEN + st0 + mrowA) * S_LEN + mcA * 4;
    const float* msrcB = amask + ((size_t)nh * S_LEN + st0 + mrowB) * S_LEN + mcB * 4;
    float* mdstA = MS + (8 * wv) * 64;
    float* mdstB = MS + (8 * wv + 4) * 64;
    // kmask (wave 0 only): lane -> chunk = lane (chunks 0-15: b0, 16-31: b1, rest pad)
    const int kmb_ = (lane >> 4) & 1;
    const float* kmsrc = kmask + (size_t)(kmb_ * NHEAD + nh) * S_LEN + (lane & 15) * 4;

    f32x4 zero4 = {0.f, 0.f, 0.f, 0.f};
    f32x4 O[4];
#pragma unroll
    for (int t = 0; t < 4; t++) O[t] = zero4;
    float mrun = -1e30f, lrun = 0.f;                 // per-lane row q = l15

    const int pk8 = l15 & 7;                          // read-side XOR key
    const int mr = stsub * 16 + l15;                  // mask row consumed

#pragma unroll 1
    for (int it = 0; it < 32; ++it) {
        const int tt = it * 64;
        // ---- cooperative staging (contiguous 1KB bursts) ----
#pragma unroll
        for (int j = 0; j < 8; ++j)
            gload16(kvsrc + tt * (wv < 2 ? HDIM : 1) + j * kvstride, kvdst + j * 512);
        gload16(msrcA + tt, mdstA);
        gload16(msrcB + tt, mdstB);
        if (wv == 0) gload16(kmsrc + tt, KM);
        __syncthreads();   // drains staging

        // ---- QK^T from LDS: aK[c][h] = K[key=16c+l15][d = g*8+32h] ----
        f32x4 sc[4];
#pragma unroll
        for (int c = 0; c < 4; c++) {
            bf16x8 aK0 = *(const bf16x8*)&KS[b][(16 * c + l15) * 64 + (g ^ pk8) * 8];
            bf16x8 aK1 = *(const bf16x8*)&KS[b][(16 * c + l15) * 64 + ((g + 4) ^ pk8) * 8];
            f32x4 s = zero4;
            s = __builtin_amdgcn_mfma_f32_16x16x32_bf16(aK0, bQ0, s, 0, 0, 0);
            s = __builtin_amdgcn_mfma_f32_16x16x32_bf16(aK1, bQ1, s, 0, 0, 0);
            sc[c] = s;
        }
        // ---- masks from LDS ----
#pragma unroll
        for (int c = 0; c < 4; c++) {
            int physm = (4 * c + g) ^ ((mr & 7) << 1);
            f32x4 mk = *(const f32x4*)&MS[mr * 64 + physm * 4];
            f32x4 km = *(const f32x4*)&KM[b * 64 + (4 * c + g) * 4];
            sc[c] += mk + km;
        }
        // ---- online softmax (per-lane row q = l15) ----
        float cm = fmaxf(fmaxf(fmaxf(sc[0][0], sc[0][1]), fmaxf(sc[0][2], sc[0][3])),
                         fmaxf(fmaxf(sc[1][0], sc[1][1]), fmaxf(sc[1][2], sc[1][3])));
        cm = fmaxf(cm, fmaxf(fmaxf(fmaxf(sc[2][0], sc[2][1]), fmaxf(sc[2][2], sc[2][3])),
                             fmaxf(fmaxf(sc[3][0], sc[3][1]), fmaxf(sc[3][2], sc[3][3]))));
        cm = fmaxf(cm, __shfl_xor(cm, 16, 64));
        cm = fmaxf(cm, __shfl_xor(cm, 32, 64));
        if (!__all(cm - mrun <= 8.0f)) {             // defer-max (T13)
            float mn = fmaxf(mrun, cm);
            float f = __expf(mrun - mn);
            mrun = mn;
            lrun *= f;
#pragma unroll
            for (int r = 0; r < 4; r++) {
                float fb = __shfl(f, 4 * g + r, 64);
#pragma unroll
                for (int dt = 0; dt < 4; dt++) O[dt][r] *= fb;
            }
        }
        float rs = 0.f;
#pragma unroll
        for (int c = 0; c < 4; c++)
#pragma unroll
            for (int r = 0; r < 4; r++) {
                float p = __expf(sc[c][r] - mrun);
                sc[c][r] = p;
                rs += p;
            }
        rs += __shfl_xor(rs, 16, 64);
        rs += __shfl_xor(rs, 32, 64);
        lrun += rs;
        // ---- P roundtrip (per-wave region; compiler inserts lgkm waits) ----
#pragma unroll
        for (int c = 0; c < 4; c++) {
            bf16x4 pk;
            pk[0] = (bf16)sc[c][0]; pk[1] = (bf16)sc[c][1];
            pk[2] = (bf16)sc[c][2]; pk[3] = (bf16)sc[c][3];
            *(bf16x4*)&P[wv][l15 * 72 + 16 * c + 4 * g] = pk;
        }
        bf16x8 aP0 = *(const bf16x8*)&P[wv][l15 * 72 + g * 8];
        bf16x8 aP1 = *(const bf16x8*)&P[wv][l15 * 72 + 32 + g * 8];
        // ---- PV from LDS: bV[dt][h] = V[k=g*8+32h][d=dt*16+l15] ----
#pragma unroll
        for (int dt = 0; dt < 4; dt++) {
            bf16x8 bV0 = *(const bf16x8*)&VS[b][(dt * 16 + l15) * 64 + (g ^ pk8) * 8];
            bf16x8 bV1 = *(const bf16x8*)&VS[b][(dt * 16 + l15) * 64 + ((g + 4) ^ pk8) * 8];
            O[dt] = __builtin_amdgcn_mfma_f32_16x16x32_bf16(aP0, bV0, O[dt], 0, 0, 0);
            O[dt] = __builtin_amdgcn_mfma_f32_16x16x32_bf16(aP1, bV1, O[dt], 0, 0, 0);
        }
        __syncthreads();   // all reads done before next stage overwrites
    }

    // ---- epilogue ----
#pragma unroll
    for (int r = 0; r < 4; r++) {
        float lq = __shfl(lrun, 4 * g + r, 64);
        float inv = 1.0f / lq;
        int s = st0s + 4 * g + r;
        int token = s * BATCH + b;
#pragma unroll
        for (int dt = 0; dt < 4; dt++) {
            int h = nh * HDIM + dt * 16 + l15;
            ctx[(size_t)token * HID + h] = (bf16)(O[dt][r] * inv);
        }
    }
}

extern "C" void kernel_launch(void* const* d_in, const int* in_sizes, int n_in,
                              void* d_out, int out_size, void* d_ws, size_t ws_size,
                              hipStream_t stream) {
    const float* hidden = (const float*)d_in[0];
    const float* amask  = (const float*)d_in[1];
    const float* kmask  = (const float*)d_in[2];
    const float* Wq = (const float*)d_in[3];
    const float* bq = (const float*)d_in[4];
    const float* Wk = (const float*)d_in[5];
    const float* bk = (const float*)d_in[6];
    const float* Wv = (const float*)d_in[7];
    const float* bv = (const float*)d_in[8];
    const float* Wo = (const float*)d_in[9];
    const float* bo = (const float*)d_in[10];
    float* out = (float*)d_out;

    char* ws = (char*)d_ws;
    bf16* Xb   = (bf16*)(ws);                       // 8 MB  [4096][1024]
    bf16* Wcat = (bf16*)(ws + (8u  << 20));         // 6 MB  [3072][1024]
    bf16* Wob  = (bf16*)(ws + (14u << 20));         // 2 MB  [1024][1024]
    bf16* qh   = (bf16*)(ws + (16u << 20));         // 8 MB  [32][2048][64]
    bf16* kh   = (bf16*)(ws + (24u << 20));         // 8 MB
    bf16* vT   = (bf16*)(ws + (32u << 20));         // 8 MB  [32][64][2048]
    bf16* ctx  = (bf16*)(ws + (40u << 20));         // 8 MB  [4096][1024]

    cvt_f32_bf16<<<2048, 256, 0, stream>>>(hidden, Xb, NTOK * HID);
    cvt_f32_bf16<<<512, 256, 0, stream>>>(Wq, Wcat,              HID * HID);
    cvt_f32_bf16<<<512, 256, 0, stream>>>(Wk, Wcat + HID * HID,  HID * HID);
    cvt_f32_bf16<<<512, 256, 0, stream>>>(Wv, Wcat + 2 * HID * HID, HID * HID);
    cvt_f32_bf16<<<512, 256, 0, stream>>>(Wo, Wob, HID * HID);

    gemm_bt<<<dim3(24, 32), 256, 0, stream>>>(Xb, Wcat, NTOK, 3 * HID, HID, 0,
                                              bq, bk, bv, bo, qh, kh, vT, nullptr);
    attn<<<dim3(64, 16), 256, 0, stream>>>(qh, kh, vT, amask, kmask, ctx);
    gemm_bt<<<dim3(8, 32), 256, 0, stream>>>(ctx, Wob, NTOK, HID, HID, 1,
                                             bq, bk, bv, bo, qh, kh, vT, out);
}

// Round 14
// 239.656 us; speedup vs baseline: 3.0050x; 1.0637x over previous
//
#include <hip/hip_runtime.h>
#include <hip/hip_bf16.h>
#include <math.h>

#define S_LEN 2048
#define BATCH 2
#define HID 1024
#define NHEAD 16
#define HDIM 64
#define NTOK (S_LEN*BATCH)   // 4096

typedef __bf16 bf16;
typedef __bf16 bf16x4 __attribute__((ext_vector_type(4)));
typedef __bf16 bf16x8 __attribute__((ext_vector_type(8)));
typedef float f32x4 __attribute__((ext_vector_type(4)));

typedef const __attribute__((address_space(1))) unsigned int* gptr_t;
typedef __attribute__((address_space(3))) unsigned int* lptr_t;

__device__ __forceinline__ void gload16(const void* g, void* l) {
    __builtin_amdgcn_global_load_lds((gptr_t)g, (lptr_t)l, 16, 0, 0);
}
__device__ __forceinline__ void gload4(const void* g, void* l) {
    __builtin_amdgcn_global_load_lds((gptr_t)g, (lptr_t)l, 4, 0, 0);
}

// ---------------- fp32 -> bf16 convert (8 elems/thread) ----------------
__global__ void cvt_f32_bf16(const float* __restrict__ src, bf16* __restrict__ dst, int n) {
    int i = (blockIdx.x * blockDim.x + threadIdx.x) * 8;
    if (i >= n) return;
    const float4* s = (const float4*)(src + i);
    float4 a = s[0], b = s[1];
    bf16x8 o;
    o[0] = (bf16)a.x; o[1] = (bf16)a.y; o[2] = (bf16)a.z; o[3] = (bf16)a.w;
    o[4] = (bf16)b.x; o[5] = (bf16)b.y; o[6] = (bf16)b.z; o[7] = (bf16)b.w;
    *(bf16x8*)(dst + i) = o;
}

// ---------------- GEMM: C[M][N] = A[M][K] * B[N][K]^T ----------------
#define BM 128
#define BN 128
#define BK 32

__global__ __launch_bounds__(256) void gemm_bt(
    const bf16* __restrict__ A, const bf16* __restrict__ B,
    int M, int N, int K, int mode,
    const float* __restrict__ bq, const float* __restrict__ bk,
    const float* __restrict__ bv, const float* __restrict__ bo,
    bf16* __restrict__ qh, bf16* __restrict__ kh, bf16* __restrict__ vT,
    float* __restrict__ outp)
{
    __shared__ __align__(16) bf16 As[BM * BK];
    __shared__ __align__(16) bf16 Bs[BN * BK];
    const int tid = threadIdx.x;
    const int lane = tid & 63, wv = tid >> 6;
    const int g = lane >> 4, l15 = lane & 15;
    const int wr = wv >> 1, wc = wv & 1;
    const int bm = blockIdx.y * BM, bn = blockIdx.x * BN;

    f32x4 zero4 = {0.f, 0.f, 0.f, 0.f};
    f32x4 acc[4][4];
#pragma unroll
    for (int mi = 0; mi < 4; mi++)
#pragma unroll
        for (int ni = 0; ni < 4; ni++) acc[mi][ni] = zero4;

    const int r0 = wv * 32 + (lane >> 2);
    const int c0 = (lane & 3) * 8;
    const bf16* Ag0 = A + (size_t)(bm + r0) * K + c0;
    const bf16* Ag1 = Ag0 + (size_t)16 * K;
    const bf16* Bg0 = B + (size_t)(bn + r0) * K + c0;
    const bf16* Bg1 = Bg0 + (size_t)16 * K;
    bf16* AsW = &As[(wv * 32) * BK];
    bf16* BsW = &Bs[(wv * 32) * BK];

    for (int k0 = 0; k0 < K; k0 += BK) {
        gload16(Ag0 + k0, AsW);
        gload16(Ag1 + k0, AsW + 16 * BK);
        gload16(Bg0 + k0, BsW);
        gload16(Bg1 + k0, BsW + 16 * BK);
        __syncthreads();

        bf16x8 aF[4], bF[4];
#pragma unroll
        for (int mi = 0; mi < 4; mi++)
            aF[mi] = *(const bf16x8*)&As[(wr * 64 + mi * 16 + l15) * BK + g * 8];
#pragma unroll
        for (int ni = 0; ni < 4; ni++)
            bF[ni] = *(const bf16x8*)&Bs[(wc * 64 + ni * 16 + l15) * BK + g * 8];
#pragma unroll
        for (int mi = 0; mi < 4; mi++)
#pragma unroll
            for (int ni = 0; ni < 4; ni++)
                acc[mi][ni] = __builtin_amdgcn_mfma_f32_16x16x32_bf16(
                    aF[mi], bF[ni], acc[mi][ni], 0, 0, 0);
        __syncthreads();
    }

    if (mode == 0) {
#pragma unroll
        for (int ni = 0; ni < 4; ni++) {
            int n = bn + wc * 64 + ni * 16 + l15;       // 0..3071
            int which = n >> 10;                         // 0=q 1=k 2=v
            int c = n & 1023;
            int nh = c >> 6, d = c & 63;
            const float* bias_p = (which == 0) ? bq : (which == 1) ? bk : bv;
            float bias = bias_p[c];
            float scl = (which == 0) ? 0.125f : 1.0f;
#pragma unroll
            for (int mi = 0; mi < 4; mi++) {
#pragma unroll
                for (int r = 0; r < 4; r++) {
                    int m = bm + wr * 64 + mi * 16 + g * 4 + r;  // token
                    int s = m >> 1, b = m & 1;
                    int head = b * NHEAD + nh;
                    bf16 val = (bf16)((acc[mi][ni][r] + bias) * scl);
                    if (which == 2)
                        vT[((size_t)(head * HDIM + d)) * S_LEN + s] = val;
                    else {
                        bf16* dst = (which == 0) ? qh : kh;
                        dst[((size_t)(head * S_LEN + s)) * HDIM + d] = val;
                    }
                }
            }
        }
    } else {
#pragma unroll
        for (int ni = 0; ni < 4; ni++) {
            int n = bn + wc * 64 + ni * 16 + l15;
            float bias = bo[n];
#pragma unroll
            for (int mi = 0; mi < 4; mi++) {
#pragma unroll
                for (int r = 0; r < 4; r++) {
                    int m = bm + wr * 64 + mi * 16 + g * 4 + r;
                    outp[(size_t)m * HID + n] = acc[mi][ni][r] + bias;
                }
            }
        }
    }
}

// ---------------- flash attention: GEMM-shaped + counted-vmcnt pipeline (T3/T4) ----------------
// grid 1024 blocks x 4 waves. Block = (b, nh, 64-row q-tile); wave wv = 16 q-rows.
// Per iter (64 keys): B1(raw) -> stage(t+1): exactly 9 global_load_lds per wave
// (2 K + 2 V + 4 mask + 1 kmask-dup) -> s_waitcnt vmcnt(9) [stage(t) landed, stage(t+1)
// STAYS IN FLIGHT] -> B2(raw) -> compute from buf(t). No vmcnt(0) drain in the loop.
__global__ __launch_bounds__(256) void attn(
    const bf16* __restrict__ q, const bf16* __restrict__ kh, const bf16* __restrict__ vT,
    const float* __restrict__ amask,   // [16][2048][2048]
    const float* __restrict__ kmask,   // [32][2048]
    bf16* __restrict__ ctx)            // [4096][1024]
{
    __shared__ __align__(16) bf16 KS[2][64 * 64];   // [buf][key][d] swz    16 KB
    __shared__ __align__(16) bf16 VS[2][64 * 64];   // [buf][d][key] swz    16 KB
    __shared__ __align__(16) float MS[2][64 * 64];  // [buf][q][k] swz      32 KB
    __shared__ __align__(16) float KM[2][64];       // [buf][k]            0.5 KB
    __shared__ __align__(16) bf16 P[4][16 * 72];    // per-wave P          9.2 KB

    const int tid = threadIdx.x, lane = tid & 63, wv = tid >> 6;
    const int g = lane >> 4, l15 = lane & 15;

    // XCD swizzle: b-twin blocks of one (nh,qt) adjacent -> same XCD (mask L2 twin-hit);
    // each XCD owns 2 heads (K/V L2-resident).
    const int hw = blockIdx.y * 64 + blockIdx.x;     // grid (64, 16)
    const int vid = (hw & 7) * 128 + (hw >> 3);
    const int nh = vid >> 6;
    const int qt = (vid & 63) >> 1;                  // 64-row q-tile, 0..31
    const int b  = vid & 1;
    const int st0 = qt * 64;
    const int st0s = st0 + wv * 16;                  // wave q-base
    const int n = b * NHEAD + nh;

    const bf16* qrow = q + ((size_t)(n * S_LEN + st0s + l15)) * HDIM;
    bf16x8 bQ0 = *(const bf16x8*)(qrow + g * 8);
    bf16x8 bQ1 = *(const bf16x8*)(qrow + 32 + g * 8);

    // ---- staging addresses (tt-independent) ----
    // K/V: instr j covers 8 rows x 128B; row = 16wv+8j+(lane>>3); chunk = (lane&7)^(lane>>3)
    const int r8 = lane >> 3;
    const int c8 = (lane & 7) ^ r8;
    const bf16* ksrc = kh + ((size_t)n * S_LEN + 16 * wv + r8) * HDIM + c8 * 8;
    const bf16* vsrc = vT + ((size_t)n * HDIM + 16 * wv + r8) * S_LEN + c8 * 8;
    // mask: instr j covers 4 rows x 256B; row = 16wv+4j+(lane>>4); col16 = (lane&15)^((row&7)<<1)
    const float* msrcJ[4];
#pragma unroll
    for (int j = 0; j < 4; j++) {
        int row = 16 * wv + 4 * j + (lane >> 4);
        int col16 = (lane & 15) ^ ((row & 7) << 1);
        msrcJ[j] = amask + ((size_t)nh * S_LEN + st0 + row) * S_LEN + col16 * 4;
    }
    // kmask: 1 dword/lane (all 4 waves dup-issue the identical load: benign)
    const float* kmsrc = kmask + (size_t)n * S_LEN + lane;

    f32x4 zero4 = {0.f, 0.f, 0.f, 0.f};
    f32x4 O[4];
#pragma unroll
    for (int t = 0; t < 4; t++) O[t] = zero4;
    float mrun = -1e30f, lrun = 0.f;                 // per-lane row q = l15

    const int pk8 = l15 & 7;                         // K/V read-side XOR key
    const int mrr = wv * 16 + l15;                   // mask row consumed

    // ---- staging macro: 9 loads/wave into buf bb for key-offset tt ----
#define STAGE(bb, tt)                                                          \
    do {                                                                       \
        gload16(ksrc + (size_t)(tt) * HDIM, &KS[bb][(16 * wv) * 64]);          \
        gload16(ksrc + (size_t)((tt) + 8) * HDIM, &KS[bb][(16 * wv + 8) * 64]);\
        gload16(vsrc + (tt), &VS[bb][(16 * wv) * 64]);                         \
        gload16(vsrc + (size_t)8 * S_LEN + (tt), &VS[bb][(16 * wv + 8) * 64]); \
        gload16(msrcJ[0] + (tt), &MS[bb][(16 * wv) * 64]);                     \
        gload16(msrcJ[1] + (tt), &MS[bb][(16 * wv + 4) * 64]);                 \
        gload16(msrcJ[2] + (tt), &MS[bb][(16 * wv + 8) * 64]);                 \
        gload16(msrcJ[3] + (tt), &MS[bb][(16 * wv + 12) * 64]);                \
        gload4(kmsrc + (tt), &KM[bb][0]);                                      \
    } while (0)

    STAGE(0, 0);   // prologue

#pragma unroll 1
    for (int it = 0; it < 32; ++it) {
        const int cur = it & 1;
        __builtin_amdgcn_s_barrier();            // B1: prev compute reads done
        if (it < 31) {
            STAGE(cur ^ 1, (it + 1) * 64);
            asm volatile("s_waitcnt vmcnt(9)" ::: "memory");   // stage(it) landed
        } else {
            asm volatile("s_waitcnt vmcnt(0)" ::: "memory");
        }
        __builtin_amdgcn_s_barrier();            // B2: ALL waves' stage(it) landed
        __builtin_amdgcn_sched_barrier(0);

        // ---- QK^T from LDS ----
        f32x4 sc[4];
#pragma unroll
        for (int c = 0; c < 4; c++) {
            bf16x8 aK0 = *(const bf16x8*)&KS[cur][(16 * c + l15) * 64 + (g ^ pk8) * 8];
            bf16x8 aK1 = *(const bf16x8*)&KS[cur][(16 * c + l15) * 64 + ((g + 4) ^ pk8) * 8];
            f32x4 s = zero4;
            s = __builtin_amdgcn_mfma_f32_16x16x32_bf16(aK0, bQ0, s, 0, 0, 0);
            s = __builtin_amdgcn_mfma_f32_16x16x32_bf16(aK1, bQ1, s, 0, 0, 0);
            sc[c] = s;
        }
        // ---- masks from LDS ----
#pragma unroll
        for (int c = 0; c < 4; c++) {
            int physm = (4 * c + g) ^ ((mrr & 7) << 1);
            f32x4 mk = *(const f32x4*)&MS[cur][mrr * 64 + physm * 4];
            f32x4 km = *(const f32x4*)&KM[cur][(4 * c + g) * 4];
            sc[c] += mk + km;
        }
        // ---- online softmax (per-lane row q = l15) ----
        float cm = fmaxf(fmaxf(fmaxf(sc[0][0], sc[0][1]), fmaxf(sc[0][2], sc[0][3])),
                         fmaxf(fmaxf(sc[1][0], sc[1][1]), fmaxf(sc[1][2], sc[1][3])));
        cm = fmaxf(cm, fmaxf(fmaxf(fmaxf(sc[2][0], sc[2][1]), fmaxf(sc[2][2], sc[2][3])),
                             fmaxf(fmaxf(sc[3][0], sc[3][1]), fmaxf(sc[3][2], sc[3][3]))));
        cm = fmaxf(cm, __shfl_xor(cm, 16, 64));
        cm = fmaxf(cm, __shfl_xor(cm, 32, 64));
        if (!__all(cm - mrun <= 8.0f)) {             // defer-max (T13)
            float mn = fmaxf(mrun, cm);
            float f = __expf(mrun - mn);
            mrun = mn;
            lrun *= f;
#pragma unroll
            for (int r = 0; r < 4; r++) {
                float fb = __shfl(f, 4 * g + r, 64);
#pragma unroll
                for (int dt = 0; dt < 4; dt++) O[dt][r] *= fb;
            }
        }
        float rs = 0.f;
#pragma unroll
        for (int c = 0; c < 4; c++)
#pragma unroll
            for (int r = 0; r < 4; r++) {
                float p = __expf(sc[c][r] - mrun);
                sc[c][r] = p;
                rs += p;
            }
        rs += __shfl_xor(rs, 16, 64);
        rs += __shfl_xor(rs, 32, 64);
        lrun += rs;
        // ---- P roundtrip (per-wave region) ----
#pragma unroll
        for (int c = 0; c < 4; c++) {
            bf16x4 pk;
            pk[0] = (bf16)sc[c][0]; pk[1] = (bf16)sc[c][1];
            pk[2] = (bf16)sc[c][2]; pk[3] = (bf16)sc[c][3];
            *(bf16x4*)&P[wv][l15 * 72 + 16 * c + 4 * g] = pk;
        }
        bf16x8 aP0 = *(const bf16x8*)&P[wv][l15 * 72 + g * 8];
        bf16x8 aP1 = *(const bf16x8*)&P[wv][l15 * 72 + 32 + g * 8];
        // ---- PV from LDS ----
#pragma unroll
        for (int dt = 0; dt < 4; dt++) {
            bf16x8 bV0 = *(const bf16x8*)&VS[cur][(dt * 16 + l15) * 64 + (g ^ pk8) * 8];
            bf16x8 bV1 = *(const bf16x8*)&VS[cur][(dt * 16 + l15) * 64 + ((g + 4) ^ pk8) * 8];
            O[dt] = __builtin_amdgcn_mfma_f32_16x16x32_bf16(aP0, bV0, O[dt], 0, 0, 0);
            O[dt] = __builtin_amdgcn_mfma_f32_16x16x32_bf16(aP1, bV1, O[dt], 0, 0, 0);
        }
    }
#undef STAGE

    // ---- epilogue ----
#pragma unroll
    for (int r = 0; r < 4; r++) {
        float lq = __shfl(lrun, 4 * g + r, 64);
        float inv = 1.0f / lq;
        int s = st0s + 4 * g + r;
        int token = s * BATCH + b;
#pragma unroll
        for (int dt = 0; dt < 4; dt++) {
            int h = nh * HDIM + dt * 16 + l15;
            ctx[(size_t)token * HID + h] = (bf16)(O[dt][r] * inv);
        }
    }
}

extern "C" void kernel_launch(void* const* d_in, const int* in_sizes, int n_in,
                              void* d_out, int out_size, void* d_ws, size_t ws_size,
                              hipStream_t stream) {
    const float* hidden = (const float*)d_in[0];
    const float* amask  = (const float*)d_in[1];
    const float* kmask  = (const float*)d_in[2];
    const float* Wq = (const float*)d_in[3];
    const float* bq = (const float*)d_in[4];
    const float* Wk = (const float*)d_in[5];
    const float* bk = (const float*)d_in[6];
    const float* Wv = (const float*)d_in[7];
    const float* bv = (const float*)d_in[8];
    const float* Wo = (const float*)d_in[9];
    const float* bo = (const float*)d_in[10];
    float* out = (float*)d_out;

    char* ws = (char*)d_ws;
    bf16* Xb   = (bf16*)(ws);                       // 8 MB  [4096][1024]
    bf16* Wcat = (bf16*)(ws + (8u  << 20));         // 6 MB  [3072][1024]
    bf16* Wob  = (bf16*)(ws + (14u << 20));         // 2 MB  [1024][1024]
    bf16* qh   = (bf16*)(ws + (16u << 20));         // 8 MB  [32][2048][64]
    bf16* kh   = (bf16*)(ws + (24u << 20));         // 8 MB
    bf16* vT   = (bf16*)(ws + (32u << 20));         // 8 MB  [32][64][2048]
    bf16* ctx  = (bf16*)(ws + (40u << 20));         // 8 MB  [4096][1024]

    cvt_f32_bf16<<<2048, 256, 0, stream>>>(hidden, Xb, NTOK * HID);
    cvt_f32_bf16<<<512, 256, 0, stream>>>(Wq, Wcat,              HID * HID);
    cvt_f32_bf16<<<512, 256, 0, stream>>>(Wk, Wcat + HID * HID,  HID * HID);
    cvt_f32_bf16<<<512, 256, 0, stream>>>(Wv, Wcat + 2 * HID * HID, HID * HID);
    cvt_f32_bf16<<<512, 256, 0, stream>>>(Wo, Wob, HID * HID);

    gemm_bt<<<dim3(24, 32), 256, 0, stream>>>(Xb, Wcat, NTOK, 3 * HID, HID, 0,
                                              bq, bk, bv, bo, qh, kh, vT, nullptr);
    attn<<<dim3(64, 16), 256, 0, stream>>>(qh, kh, vT, amask, kmask, ctx);
    gemm_bt<<<dim3(8, 32), 256, 0, stream>>>(ctx, Wob, NTOK, HID, HID, 1,
                                             bq, bk, bv, bo, qh, kh, vT, out);
}